// Round 9
// baseline (2959.693 us; speedup 1.0000x reference)
//
#include <hip/hip_runtime.h>
#include <cstdint>
#include <cstddef>

// PlainRNN fused: h_{t+1} = tanh(h_t @ W_eff + b_eff), traj[t] = h_t @ W_h2o + b_h2o
// W_eff = W_h2h + W_h2o @ W_i2h
//
// 16 groups (16 batch rows) x 16 members. Same-XCD groups (HW_REG_XCC_ID + slot ctr).
// PROVEN: agent atomic store <-> agent atomic load is the ONLY working poll channel
// (R4/R7 sc0-polls froze). Data path: plain stores -> local L2, cold plain loads (R5).
//
// R9 restructure (R5..R8 showed barrier micro-tuning is not the lever):
//  - UNIFORM member work: member m owns hidden cols [64m,64m+64) + y cols [8m,8m+8)
//    (old 72-col map made members 14/15 systematic stragglers via y-stores).
//  - Per-(member,wave) flags: wave posts its own flag after ITS stores drain
//    (s_waitcnt vmcnt(0)); no all-wave drain barrier on the arrival path.
//  - Per-wave gating: consumer wave wv's K-slice [256wv,256wv+256) is produced by
//    exactly members 4wv..4wv+3 => gate on 16 contiguous flags, one 64B agent load.
//    Waves start compute as soon as THEIR producers posted (detect overlaps compute).
//  - Double-buffered LDS reduce (t&1) => ONE __syncthreads per step total.

#define BATCH  256
#define INPUT  128
#define HIDDEN 1024
#define OUTPUT 128
#define TSTEPS 512
#define NCAT   1152
#define GROUPS 16
#define MEMB   16
#define NSLOT  4

// workspace layout (bytes)
#define WS_WFRAG 0u
#define WS_BEFF  2621440u
#define WS_HBUF  2629632u                 // 4 slots x 256x1024 f16
#define WS_BAR   4726784u
// bar[] u32: [0..1023]  flags: group g at g*64; flag[(m,w)] = g*64 + m*4 + w
//            [1024 + xcc*32] per-XCD slot counters (one-time)
#define BAR_U32S 1280

typedef _Float16 f16;
typedef _Float16 v8h __attribute__((ext_vector_type(8)));
typedef float    v4f __attribute__((ext_vector_type(4)));

__device__ __forceinline__ float fast_tanh(float x){
  float e = __expf(2.0f * x);
  return (e - 1.0f) / (e + 1.0f);
}

// ---- bias composition: [0..1023] hidden bias, [1024..1151] y bias
__global__ void k_bias(const float* __restrict__ bi2h, const float* __restrict__ bh2h,
                       const float* __restrict__ bh2o, const float* __restrict__ Wi2h,
                       float* __restrict__ beff){
  int n = blockIdx.x*256 + threadIdx.x;
  if (n >= 1168) return;
  float v = 0.f;
  if (n < HIDDEN){
    v = bi2h[n] + bh2h[n];
    for (int j=0;j<INPUT;j++) v += bh2o[j]*Wi2h[j*HIDDEN + n];
  } else if (n < NCAT){
    v = bh2o[n - HIDDEN];
  }
  beff[n] = v;
}

// ---- h_1 = tanh(x0 @ W_i2h + b_i2h + b_h2h) -> slot 0
__global__ void k_h1(const float* __restrict__ x0, const float* __restrict__ Wi2h,
                     const float* __restrict__ bi2h, const float* __restrict__ bh2h,
                     f16* __restrict__ hbuf){
  int idx = blockIdx.x*256 + threadIdx.x;
  int m = idx >> 10, n = idx & 1023;
  float acc = bi2h[n] + bh2h[n];
  const float* xr = x0 + m*INPUT;
  for (int j=0;j<INPUT;j++) acc += xr[j]*Wi2h[j*HIDDEN + n];
  hbuf[idx] = (f16)fast_tanh(acc);
}

// ---- traj[0] = x_0
__global__ void k_copy0(const float* __restrict__ x0, float* __restrict__ out){
  int i = blockIdx.x*256 + threadIdx.x;
  out[i] = x0[i];
}

// ---- W fragment packing: [mem 16][wave 4][kk 8][c 5][lane 64][8 halves]
// NEW column map: c<4 -> hidden col 64*mem + 16c + l15 ; c==4,l15<8 -> y col 8*mem + l15
__global__ void k_wfrag(const float* __restrict__ Wh2h, const float* __restrict__ Wh2o,
                        const float* __restrict__ Wi2h, f16* __restrict__ Wfrag){
  int gid = blockIdx.x*256 + threadIdx.x;     // 0..163839
  int lane = gid & 63;
  int fi = gid >> 6;
  int c = fi % 5, kk = (fi/5) & 7, wv = (fi/40) & 3, mem = fi/160;
  int k0 = wv*256 + kk*32 + (lane>>4)*8;
  int l15 = lane & 15;
  f16 vals[8];
  if (c == 4){
    if (l15 < 8){
      int jy = mem*8 + l15;
      #pragma unroll
      for (int j=0;j<8;j++) vals[j] = (f16)Wh2o[(k0+j)*OUTPUT + jy];
    } else {
      #pragma unroll
      for (int j=0;j<8;j++) vals[j] = (f16)0.f;
    }
  } else {
    int n = mem*64 + c*16 + l15;   // hidden col, always < 1024
    float acc[8];
    #pragma unroll
    for (int j=0;j<8;j++) acc[j] = Wh2h[(k0+j)*HIDDEN + n];
    for (int q=0;q<INPUT;q++){
      float wi = Wi2h[q*HIDDEN + n];
      #pragma unroll
      for (int j=0;j<8;j++) acc[j] += Wh2o[(k0+j)*OUTPUT + q]*wi;
    }
    #pragma unroll
    for (int j=0;j<8;j++) vals[j] = (f16)acc[j];
  }
  v8h pack;
  #pragma unroll
  for (int j=0;j<8;j++) pack[j] = vals[j];
  *(v8h*)(Wfrag + (size_t)gid*8) = pack;
}

// ---- persistent recurrence kernel: 256 blocks x 256 threads, 1 block/CU (96KB dyn LDS)
__global__ void __launch_bounds__(256, 1)
k_rnn(const f16* __restrict__ Wfrag, const float* __restrict__ beff,
      f16* __restrict__ hbuf, unsigned int* __restrict__ bar,
      float* __restrict__ out){
  extern __shared__ char lds_raw[];
  float*    red    = (float*)lds_raw;              // 2 buffers x 16KB ([(c*3+rank)][lane][4])
  unsigned* s_slot = (unsigned*)(lds_raw + 32768);

  const int tid  = threadIdx.x;
  const int lane = tid & 63;
  const int wv   = tid >> 6;

  // Dynamic same-XCD group formation: group shares one XCD L2 BY CONSTRUCTION.
  if (tid == 0){
    unsigned xcc;
    asm volatile("s_getreg_b32 %0, hwreg(HW_REG_XCC_ID)" : "=s"(xcc));
    xcc &= 7;
    unsigned slot = atomicAdd(&bar[1024 + xcc*32], 1u);  // one-time, device-scope
    *s_slot = xcc*32 + (slot & 31u);
  }
  __syncthreads();
  const unsigned sid = *s_slot;
  const int g   = sid >> 4;
  const int mem = sid & 15;
  if (g >= GROUPS) return;
  const int m0   = g * 16;
  const int quad = lane >> 4;
  const int l15  = lane & 15;

  // B fragments resident in registers for the whole 511-step loop
  v8h bw[8][5];
  {
    const f16* wp = Wfrag + ((size_t)((mem*4 + wv)*40)*64 + lane)*8;
    #pragma unroll
    for (int kk=0;kk<8;kk++)
      #pragma unroll
      for (int c=0;c<5;c++)
        bw[kk][c] = *(const v8h*)(wp + (size_t)((kk*5+c)*64)*8);
  }

  const int kbase = wv*256;
  unsigned int* flags = bar + g*64;     // 64 flags per group: [m*4 + w]

  // epilogue constants (uniform across members now)
  const int  colA   = mem*64 + wv*16 + l15;        // hidden col, always < 1024
  const float biasA = beff[colA];
  const bool hasY   = (wv == 0) && (l15 < 8);
  const int  ycol   = mem*8 + l15;
  const float biasY = hasY ? beff[HIDDEN + ycol] : 0.f;
  const size_t hoffA = (size_t)(m0 + quad*4)*HIDDEN + colA;
  const size_t yoffA = (size_t)(m0 + quad*4)*OUTPUT + ycol;

  for (int t=1; t<TSTEPS; ++t){
    // ---- per-wave gate: my K-slice's producers are members 4wv..4wv+3, all 4 waves
    // each => 16 contiguous flags [16wv .. 16wv+16). One coalesced 64B agent load.
    {
      const unsigned want = (unsigned)(t-1);
      unsigned tries = 0;
      for (;;){
        unsigned f = want;
        if (lane < 16)
          f = __hip_atomic_load(&flags[16*wv + lane], __ATOMIC_RELAXED, __HIP_MEMORY_SCOPE_AGENT);
        unsigned long long b = __ballot(f >= want);
        if (b == ~0ull) break;
        if (++tries >= 2048u) break;     // bounded: fail visibly, never hang
        __builtin_amdgcn_s_sleep(1);
      }
      asm volatile("" ::: "memory");     // no A-load hoisting above the gate
    }

    const f16* hin  = hbuf + (size_t)((t-1)&(NSLOT-1))*(BATCH*HIDDEN);
    f16*       hout = hbuf + (size_t)(t&(NSLOT-1))*(BATCH*HIDDEN);

    // A fragments: plain vector loads; 4-slot rotation => L1 capacity-evicted,
    // fresh hits in the shared XCD L2. lane = A[m=l15][k=quad*8+j].
    v8h af[8];
    {
      const v8h* abase = (const v8h*)(hin + (size_t)(m0 + l15)*HIDDEN + kbase + quad*8);
      #pragma unroll
      for (int kk=0;kk<8;kk++)
        af[kk] = abase[kk*4];
    }

    v4f acc[5];
    #pragma unroll
    for (int c=0;c<5;c++){ v4f z = {0.f,0.f,0.f,0.f}; acc[c] = z; }

    #pragma unroll
    for (int kk=0;kk<8;kk++){
      #pragma unroll
      for (int c=0;c<5;c++)
        acc[c] = __builtin_amdgcn_mfma_f32_16x16x32_f16(af[kk], bw[kk][c], acc[c], 0,0,0);
    }

    // cross-wave K reduction via LDS, DOUBLE-BUFFERED (t&1): one barrier per step.
    float* rw = red + (size_t)(t & 1)*4096;
    #pragma unroll
    for (int c=0;c<5;c++){
      int owner = c & 3;                 // tiles 0..3 -> waves 0..3; tile 4 -> wave 0
      if (wv != owner){
        int rank = (wv > owner) ? wv-1 : wv;
        *(v4f*)(rw + ((size_t)(c*3 + rank)*64 + lane)*4) = acc[c];
      }
    }
    __syncthreads();                     // the ONLY barrier in the step

    // owner sums
    v4f sA = acc[wv];
    #pragma unroll
    for (int r=0;r<3;r++) sA += *(const v4f*)(rw + ((size_t)(wv*3 + r)*64 + lane)*4);
    v4f sY = acc[4];
    if (wv == 0){
      #pragma unroll
      for (int r=0;r<3;r++) sY += *(const v4f*)(rw + ((size_t)(4*3 + r)*64 + lane)*4);
    }

    // y stores first (uniform 8 cols/member), then h stores; one drain covers both
    if (hasY){
      float* op = out + (size_t)t*(BATCH*OUTPUT) + yoffA;
      #pragma unroll
      for (int r=0;r<4;r++) op[(size_t)r*OUTPUT] = sY[r] + biasY;
    }
    #pragma unroll
    for (int r=0;r<4;r++)
      hout[hoffA + (size_t)r*HIDDEN] = (f16)fast_tanh(sA[r] + biasA);  // C/D: col=l15,row=quad*4+r

    // per-wave arrival: drain OWN stores to L2, then post OWN flag (agent store).
    asm volatile("s_waitcnt vmcnt(0)" ::: "memory");
    if (lane == 0)
      __hip_atomic_store(&flags[mem*4 + wv], (unsigned)t, __ATOMIC_RELAXED, __HIP_MEMORY_SCOPE_AGENT);
  }
}

extern "C" void kernel_launch(void* const* d_in, const int* in_sizes, int n_in,
                              void* d_out, int out_size, void* d_ws, size_t ws_size,
                              hipStream_t stream){
  const float* x0   = (const float*)d_in[0];
  const float* Wi2h = (const float*)d_in[1];
  const float* bi2h = (const float*)d_in[2];
  const float* Wh2h = (const float*)d_in[3];
  const float* bh2h = (const float*)d_in[4];
  const float* Wh2o = (const float*)d_in[5];
  const float* bh2o = (const float*)d_in[6];
  float* out = (float*)d_out;
  char* ws = (char*)d_ws;

  f16*          Wfrag = (f16*)(ws + WS_WFRAG);
  float*        beff  = (float*)(ws + WS_BEFF);
  f16*          hbuf  = (f16*)(ws + WS_HBUF);
  unsigned int* bar   = (unsigned int*)(ws + WS_BAR);

  hipMemsetAsync(bar, 0, BAR_U32S*sizeof(unsigned int), stream);
  k_bias <<<5,    256, 0, stream>>>(bi2h, bh2h, bh2o, Wi2h, beff);
  k_h1   <<<1024, 256, 0, stream>>>(x0, Wi2h, bi2h, bh2h, hbuf);
  k_copy0<<<128,  256, 0, stream>>>(x0, out);
  k_wfrag<<<640,  256, 0, stream>>>(Wh2h, Wh2o, Wi2h, Wfrag);

  // 96KB dynamic LDS forces 1 block/CU -> 256 blocks co-resident, 32 per XCD,
  // 1 wave/SIMD -> full VGPR budget for register-resident W fragments.
  hipFuncSetAttribute((const void*)k_rnn, hipFuncAttributeMaxDynamicSharedMemorySize, 98304);
  k_rnn<<<256, 256, 98304, stream>>>(Wfrag, beff, hbuf, bar, out);
}